// Round 15
// baseline (4373.675 us; speedup 1.0000x reference)
//
#include <hip/hip_runtime.h>
#include <math.h>

#define T_ 256
#define H_ 512
#define NWG 256
#define NTHR 256
#define WPG 64      // WGs per batch-group (4 groups of 32 batches)

typedef _Float16 half8 __attribute__((ext_vector_type(8)));
typedef float f32x4 __attribute__((ext_vector_type(4)));
typedef unsigned short u16;
typedef unsigned int u32;
typedef unsigned long long u64;

// ---- ws byte offsets ----
// h planes: fp16, rings of 16 slots (slot = step & 15), each slot 128 KB,
// tiled [kchunk16][b128][k32] f16. Groups touch disjoint 64B b-rows.
#define O_H0R  0u           // 16 x 131072 = 2 MB
#define O_H1R  2097152u     // 16 x 131072 = 2 MB
#define O_BAR  4194304u     // 256 flags x 64 B

// ---- LDS byte offsets (131072 dynamic, single-f16 weight planes, 32 rows/WG) ----
#define E0W 0u             // 32 rows x 576  (x|h0), row 1152 B  = 36 KB
#define E1W 36864u         // 32 rows x 1024 (h0|h1), row 2048 B = 64 KB
#define D0W 0u             // 32 rows x 1024 (Weff|dWhh0) = 64 KB
#define D1W 65536u         // 32 rows x 1024 (dWih1|dWhh1) = 64 KB

__device__ __forceinline__ float sigf(float x) { return 1.0f / (1.0f + expf(-x)); }

__device__ __forceinline__ u16 f2h_bits(float f) {
    _Float16 h = (_Float16)f;
    return __builtin_bit_cast(u16, h);
}
__device__ __forceinline__ float h2f(u16 x) {
    return (float)__builtin_bit_cast(_Float16, x);
}

// Producer-side stores: agent-scope write-through (visible at MALL, no dirty L2 lines).
__device__ __forceinline__ void llc_store64(u64* p, u64 v) {
    __hip_atomic_store(p, v, __ATOMIC_RELAXED, __HIP_MEMORY_SCOPE_AGENT);
}
__device__ __forceinline__ void llc_store32(u32* p, u32 v) {
    __hip_atomic_store(p, v, __ATOMIC_RELAXED, __HIP_MEMORY_SCOPE_AGENT);
}

// ---- split-phase group barrier: atomic-free flags + wave-parallel poll ----
// arrive: drain own stores, then ONE sc1 store to this WG's private flag line.
__device__ __forceinline__ void gbar_arrive(int* flags, int w, int gen) {
    asm volatile("s_waitcnt vmcnt(0)" ::: "memory");
    __syncthreads();
    if (threadIdx.x == 0)
        __hip_atomic_store(flags + w * 16, gen, __ATOMIC_RELAXED, __HIP_MEMORY_SCOPE_AGENT);
}
// wait: wave 0's 64 lanes poll the group's 64 flags in parallel; acquire fence
// (cheap, ~0.1us: r9-vs-r10) EVERY phase -- makes all read distances stale-safe.
__device__ __forceinline__ void gbar_wait(int* flags, int gbase, int gen) {
    if (threadIdx.x < 64) {
        while (__hip_atomic_load(flags + (gbase + threadIdx.x) * 16,
                                 __ATOMIC_RELAXED, __HIP_MEMORY_SCOPE_AGENT) < gen)
            __builtin_amdgcn_s_sleep(1);
    }
    __syncthreads();
    if (threadIdx.x == 0) __builtin_amdgcn_fence(__ATOMIC_ACQUIRE, "agent");
    __syncthreads();
}

// store one weight element as single f16 into swizzled LDS plane (32 rows)
__device__ __forceinline__ void st_w(char* smem, unsigned base, unsigned K2,
                                     unsigned m, unsigned k, float v) {
    _Float16 hh = (_Float16)v;
    unsigned off = (m * K2 + k * 2) ^ ((m & 7) << 4);
    *(u16*)(smem + base + off) = __builtin_bit_cast(u16, hh);
}

// Issue ALL 16 chunk-loads of one f16 plane slice (uint4 = 8 f16 per lane per chunk).
__device__ __forceinline__ void load_plane(uint4 (&buf)[16], const u32* __restrict__ plane,
                                           unsigned loff) {
    #pragma unroll
    for (int i = 0; i < 16; ++i)
        buf[i] = *(const uint4*)(plane + (size_t)i * 2048 + loff);
}

// Consume one plane: B direct from registers, A row R from swizzled LDS f16.
__device__ __forceinline__ void cons_plane(const uint4 (&buf)[16], const char* __restrict__ smem,
                                           unsigned base, unsigned K2, unsigned wk0,
                                           unsigned R, unsigned qq, f32x4& acc) {
    const unsigned swz = (R & 7) << 4;
    #pragma unroll
    for (int i = 0; i < 16; ++i) {
        const unsigned wb = R * K2 + (wk0 + (unsigned)i * 32 + qq * 8) * 2;
        half8 av = *(const half8*)(smem + base + (wb ^ swz));
        half8 bv = __builtin_bit_cast(half8, buf[i]);
        acc = __builtin_amdgcn_mfma_f32_16x16x32_f16(av, bv, acc, 0, 0, 0);
    }
}

// encoder cell-A x-segment (K=64): B built on the fly from fp32 x rows (read-only)
__device__ __forceinline__ void seg_x(
    const char* smem, unsigned base, unsigned K2,
    const float* __restrict__ x, int t, unsigned bt, unsigned R, int lane, f32x4& acc) {
    const unsigned mm = lane & 15, qq = lane >> 4;
    const unsigned swz = (R & 7) << 4;
    const float* xp = x + ((size_t)(bt + mm) * T_ + t) * 64 + qq * 8;
    #pragma unroll
    for (int i = 0; i < 2; ++i) {
        float4 f0 = *(const float4*)(xp + i * 32);
        float4 f1 = *(const float4*)(xp + i * 32 + 4);
        float fs[8] = { f0.x, f0.y, f0.z, f0.w, f1.x, f1.y, f1.z, f1.w };
        half8 bv;
        #pragma unroll
        for (int j = 0; j < 8; ++j) bv[j] = (_Float16)fs[j];
        unsigned wb = (R * K2 + (qq * 8 + i * 32) * 2) ^ swz;
        half8 av = *(const half8*)(smem + base + wb);
        acc = __builtin_amdgcn_mfma_f32_16x16x32_f16(av, bv, acc, 0, 0, 0);
    }
}

// LSTM epilogue: lane owns 4 gate preacts of one (u,b); c in register.
// h -> f16; pair-pack with lane^16 (u and u+-1) -> one u32 sc1 store per pair.
__device__ __forceinline__ void epilogue_reg(f32x4 acc, const float* bz, int u, int b,
                                             float& cr, u32* hw, int lane) {
    float gi = sigf(acc[0] + bz[0]);
    float gf = sigf(acc[1] + bz[1]);
    float gt = tanhf(acc[2] + bz[2]);
    float go = sigf(acc[3] + bz[3]);
    float cn = gf * cr + gi * gt;
    cr = cn;
    float hv = go * tanhf(cn);
    u16 mybits = f2h_bits(hv);
    int other = __shfl_xor((int)(u32)mybits, 16);
    if (((lane >> 4) & 1) == 0) {   // even-u member of the pair stores
        u32 pk = (u32)mybits | (((u32)other & 0xFFFFu) << 16);
        unsigned idx = (unsigned)(u >> 5) * 2048 + (unsigned)b * 16 + ((unsigned)(u & 31) >> 1);
        llc_store32(hw + idx, pk);
    }
}

// out(t) = h1 @ linW.T + linb; group WG wl: batch bl = g*32 + (wl>>1), f-half = wl&1.
__device__ __forceinline__ void linear_out(const u32* __restrict__ h1p,
                                           const float* __restrict__ linW,
                                           const float* __restrict__ linb,
                                           float* __restrict__ out, int g, int wl,
                                           int tid, int t) {
    const int bl = g * 32 + (wl >> 1);
    const int kq = tid & 7;
    const int f  = (wl & 1) * 32 + (tid >> 3);
    float s = 0.f;
    #pragma unroll
    for (int c2 = 0; c2 < 2; ++c2) {
        const int ch = kq * 2 + c2;   // k chunk = k>>5
        const u64* ph = (const u64*)h1p + (size_t)ch * 1024 + (size_t)bl * 8;
        const float* wp = linW + (size_t)f * H_ + ch * 32;
        #pragma unroll
        for (int j = 0; j < 8; ++j) {     // each u64 = 4 f16
            u64 r = ph[j];
            s += h2f((u16)r)         * wp[4 * j + 0];
            s += h2f((u16)(r >> 16)) * wp[4 * j + 1];
            s += h2f((u16)(r >> 32)) * wp[4 * j + 2];
            s += h2f((u16)(r >> 48)) * wp[4 * j + 3];
        }
    }
    s += __shfl_xor(s, 1);
    s += __shfl_xor(s, 2);
    s += __shfl_xor(s, 4);
    if (kq == 0)
        out[((size_t)bl * T_ + (255 - t)) * 64 + f] = s + linb[f];
}

__global__ __launch_bounds__(NTHR, 1) void lstm_persist(
    const float* __restrict__ x,
    const float* __restrict__ eWih0, const float* __restrict__ eWhh0,
    const float* __restrict__ ebih0, const float* __restrict__ ebhh0,
    const float* __restrict__ eWih1, const float* __restrict__ eWhh1,
    const float* __restrict__ ebih1, const float* __restrict__ ebhh1,
    const float* __restrict__ dWih0, const float* __restrict__ dWhh0,
    const float* __restrict__ dbih0, const float* __restrict__ dbhh0,
    const float* __restrict__ dWih1, const float* __restrict__ dWhh1,
    const float* __restrict__ dbih1, const float* __restrict__ dbhh1,
    const float* __restrict__ linW,  const float* __restrict__ linb,
    float* __restrict__ out, char* __restrict__ wsb, int* __restrict__ flags) {
    extern __shared__ char smem[];
    const int w = blockIdx.x, tid = threadIdx.x;
    const int lane = tid & 63, wave = tid >> 6;   // wave 0..3

    // group structure: 4 groups x 64 WGs; group owns 32 batches, WG owns 8 u's.
    const int g = w >> 6;
    const int wl = w & 63;
    const int gbase = g * WPG;
    const int u_base = wl * 8;
    const int mh = wave >> 1;                 // m-half: rows [mh*16, mh*16+16)
    const int bh = wave & 1;                  // b-half within group's 32 batches
    const int u = u_base + mh * 4 + (lane >> 4);
    const unsigned bt = (unsigned)(g * 32 + bh * 16);
    const int b = (int)bt + (lane & 15);
    const unsigned R = (unsigned)(mh * 16 + (lane & 15));   // LDS A row (0..31)
    const unsigned qq = (unsigned)(lane >> 4);
    const unsigned loff = (bt + (unsigned)(lane & 15)) * 16 + qq * 4;

    // ring-slot accessors: slot = step & 15; negative steps wrap (two's complement &).
    #define H0S(t) ((u32*)(wsb + O_H0R + (unsigned)((t) & 15) * 131072u))
    #define H1S(t) ((u32*)(wsb + O_H1R + (unsigned)((t) & 15) * 131072u))
    int gen = 0;

    // ================= INIT (group-local) =================
    {   // zero this group's b-slice of h0 slot15, h1 slots 14,15
        const int gtid = wl * NTHR + tid;     // 0..16383 within group
        if (gtid < 12288) {
            const int slot  = gtid >> 12;             // 0..2
            const int rem   = gtid & 4095;
            const int chunk = rem >> 8;
            const int brow  = (rem & 255) >> 3;
            const int q     = rem & 7;
            u64* base = (slot == 0) ? (u64*)(wsb + O_H0R + 15u * 131072u)
                      : (slot == 1) ? (u64*)(wsb + O_H1R + 14u * 131072u)
                                    : (u64*)(wsb + O_H1R + 15u * 131072u);
            llc_store64(base + (size_t)chunk * 1024 + (size_t)(g * 32 + brow) * 8 + q, 0ULL);
        }
    }
    // per-lane bias registers (incl. beff fold); c in registers
    float bzA[4], bzB[4], bzD0[4], bzD0b[4], bzD1[4];
    #pragma unroll
    for (int gg = 0; gg < 4; ++gg) {
        const int gr = gg * H_ + u;
        bzA[gg] = ebih0[gr] + ebhh0[gr];
        bzB[gg] = ebih1[gr] + ebhh1[gr];
        float d0 = dbih0[gr] + dbhh0[gr];
        bzD0[gg] = d0;
        float s = 0.f;
        for (int f = 0; f < 64; ++f) s += dWih0[(size_t)gr * 64 + f] * linb[f];
        bzD0b[gg] = d0 + s;
        bzD1[gg] = dbih1[gr] + dbhh1[gr];
    }
    float c0r = 0.f, c1r = 0.f;

    // encoder weights -> swizzled LDS f16 (32 rows: 8 u's x 4 gates)
    for (int mr = 0; mr < 32; ++mr) {
        const int gr = (mr & 3) * H_ + u_base + (mr >> 2);
        for (int k = tid; k < 576; k += NTHR) {
            float v = (k < 64) ? eWih0[(size_t)gr * 64 + k] : eWhh0[(size_t)gr * H_ + (k - 64)];
            st_w(smem, E0W, 1152, mr, k, v);
        }
        for (int k = tid; k < 1024; k += NTHR) {
            float v = (k < 512) ? eWih1[(size_t)gr * H_ + k] : eWhh1[(size_t)gr * H_ + (k - 512)];
            st_w(smem, E1W, 2048, mr, k, v);
        }
    }
    gbar_arrive(flags, w, ++gen);
    gbar_wait(flags, gbase, gen);

    uint4 P[16], Q[16], Pprev[16];

    // ================= ENCODER: depth-3 pipeline, 258 phases =================
    // phase p: cellA(t=p) || cellB(t=p-2). cellB's h0-cross input is the
    // register-carried plane loaded fresh in phase p-1 (Pprev) -> pre-wait consume.
    for (int p = 0; p <= T_ + 1; ++p) {
        gbar_arrive(flags, w, ++gen);
        f32x4 a = {0,0,0,0}, e = {0,0,0,0};
        // ---- pre-wait (hidden under poll): x-segment + cellB h0-cross from regs ----
        if (p < T_)  seg_x(smem, E0W, 1152, x, p, bt, R, lane, a);
        if (p >= 2)  cons_plane(Pprev, smem, E1W, 2048, 0, R, qq, e);   // h0(p-2)
        gbar_wait(flags, gbase, gen);
        // ---- post-wait: fresh planes only ----
        if (p <= T_) load_plane(P, H0S(p - 1), loff);                   // h0(p-1)
        if (p < T_)  cons_plane(P, smem, E0W, 1152, 64, R, qq, a);
        if (p >= 2) {
            load_plane(Q, H1S(p - 3), loff);                            // h1(p-3)
            cons_plane(Q, smem, E1W, 2048, 512, R, qq, e);
        }
        if (p < T_)  epilogue_reg(a, bzA, u, b, c0r, H0S(p), lane);
        if (p >= 2)  epilogue_reg(e, bzB, u, b, c1r, H1S(p - 2), lane);
        // carry fresh h0 plane into next phase's cellB cross input (reg copy, ~27ns)
        #pragma unroll
        for (int i = 0; i < 16; ++i) Pprev[i] = P[i];
    }

    // ================= TRANSITION: decoder weights -> LDS (WG-local) =================
    __syncthreads();
    for (int mr = 0; mr < 32; ++mr) {
        const int gr = (mr & 3) * H_ + u_base + (mr >> 2);
        const float* wr = dWih0 + (size_t)gr * 64;
        for (int c = tid; c < 512; c += NTHR) {
            float s = 0.f;
            #pragma unroll 8
            for (int f = 0; f < 64; ++f) s += wr[f] * linW[(size_t)f * H_ + c];  // Weff
            st_w(smem, D0W, 2048, mr, c, s);
            st_w(smem, D0W, 2048, mr, 512 + c, dWhh0[(size_t)gr * H_ + c]);
            st_w(smem, D1W, 2048, mr, c,       dWih1[(size_t)gr * H_ + c]);
            st_w(smem, D1W, 2048, mr, 512 + c, dWhh1[(size_t)gr * H_ + c]);
        }
    }
    __syncthreads();

    // ================= DECODER: 512 phases, 1 fresh plane-load per phase =================
    // Register carry: P holds h1(t-1) (loaded in dec0), Q holds h0 (loaded in dec1).
    // Stale-register half + linear_out are consumed PRE-wait (split-phase).
    for (int t = 0; t < T_; ++t) {
        {   // ---- dec0(t): Weff.h1(t-1) (or x-proj at t=0) + dWhh0.h0(t-1) ----
            gbar_arrive(flags, w, ++gen);
            f32x4 a = {0,0,0,0};
            if (t > 0) {
                cons_plane(Q, smem, D0W, 2048, 512, R, qq, a);   // pre-wait: h0(t-1) in regs
            } else {
                const float* xr = x + ((size_t)b * T_ + (T_ - 1)) * 64;
                #pragma unroll
                for (int gg = 0; gg < 4; ++gg) {
                    const float* wr = dWih0 + (size_t)(gg * H_ + u) * 64;
                    float s = 0.f;
                    for (int f = 0; f < 64; ++f) s += wr[f] * xr[f];
                    a[gg] = s;
                }
            }
            gbar_wait(flags, gbase, gen);
            if (t > 0) {
                load_plane(P, H1S(t - 1), loff);                 // fresh h1(t-1)
                cons_plane(P, smem, D0W, 2048, 0, R, qq, a);
            } else {
                load_plane(Q, H0S(-1), loff);                    // h0(-1) = enc h0(255)
                cons_plane(Q, smem, D0W, 2048, 512, R, qq, a);
            }
            epilogue_reg(a, (t > 0) ? bzD0b : bzD0, u, b, c0r, H0S(t), lane);
        }
        {   // ---- dec1(t): dWih1.h0(t) + dWhh1.h1(t-1) ----
            gbar_arrive(flags, w, ++gen);
            f32x4 e = {0,0,0,0};
            if (t > 0) {
                cons_plane(P, smem, D1W, 2048, 512, R, qq, e);   // pre-wait: h1(t-1) in regs
                linear_out(H1S(t - 1), linW, linb, out, g, wl, tid, t - 1);  // off crit path
            }
            gbar_wait(flags, gbase, gen);
            load_plane(Q, H0S(t), loff);                         // fresh h0(t)
            if (t == 0) {
                load_plane(P, H1S(-1), loff);                    // h1(-1) = enc h1(255)
                cons_plane(P, smem, D1W, 2048, 512, R, qq, e);
            }
            cons_plane(Q, smem, D1W, 2048, 0, R, qq, e);
            epilogue_reg(e, bzD1, u, b, c1r, H1S(t), lane);
        }
    }
    // final output (t=255): needs ALL group WGs' h1(255) -> proper group barrier
    gbar_arrive(flags, w, ++gen);
    gbar_wait(flags, gbase, gen);
    linear_out(H1S(255), linW, linb, out, g, wl, tid, 255);
}

extern "C" void kernel_launch(void* const* d_in, const int* in_sizes, int n_in,
                              void* d_out, int out_size, void* d_ws, size_t ws_size,
                              hipStream_t stream) {
    (void)in_sizes; (void)n_in; (void)out_size; (void)ws_size;
    const float* x     = (const float*)d_in[0];
    const float* eWih0 = (const float*)d_in[1];
    const float* eWhh0 = (const float*)d_in[2];
    const float* ebih0 = (const float*)d_in[3];
    const float* ebhh0 = (const float*)d_in[4];
    const float* eWih1 = (const float*)d_in[5];
    const float* eWhh1 = (const float*)d_in[6];
    const float* ebih1 = (const float*)d_in[7];
    const float* ebhh1 = (const float*)d_in[8];
    const float* dWih0 = (const float*)d_in[9];
    const float* dWhh0 = (const float*)d_in[10];
    const float* dbih0 = (const float*)d_in[11];
    const float* dbhh0 = (const float*)d_in[12];
    const float* dWih1 = (const float*)d_in[13];
    const float* dWhh1 = (const float*)d_in[14];
    const float* dbih1 = (const float*)d_in[15];
    const float* dbhh1 = (const float*)d_in[16];
    const float* linW  = (const float*)d_in[17];
    const float* linb  = (const float*)d_in[18];

    char* wsb  = (char*)d_ws;
    int* flags = (int*)(wsb + O_BAR);

    static const int lds_bytes = 131072;
    hipFuncSetAttribute((const void*)lstm_persist,
                        hipFuncAttributeMaxDynamicSharedMemorySize, lds_bytes);

    hipMemsetAsync(flags, 0, NWG * 64, stream);

    hipLaunchKernelGGL(lstm_persist, dim3(NWG), dim3(NTHR), lds_bytes, stream,
                       x, eWih0, eWhh0, ebih0, ebhh0, eWih1, eWhh1, ebih1, ebhh1,
                       dWih0, dWhh0, dbih0, dbhh0, dWih1, dWhh1, dbih1, dbhh1,
                       linW, linb, (float*)d_out, wsb, flags);
}

// Round 16
// 3731.020 us; speedup vs baseline: 1.1722x; 1.1722x over previous
//
#include <hip/hip_runtime.h>
#include <math.h>

#define T_ 256
#define H_ 512
#define NWG 256
#define NTHR 256
#define WPG 64      // WGs per batch-group (4 groups of 32 batches)

typedef _Float16 half8 __attribute__((ext_vector_type(8)));
typedef float f32x4 __attribute__((ext_vector_type(4)));
typedef unsigned short u16;
typedef unsigned int u32;
typedef unsigned long long u64;

// ---- ws byte offsets ----
// h planes: fp16, rings of 16 slots (slot = step & 15), each slot 128 KB,
// tiled [kchunk16][b128][k32] f16. Groups touch disjoint 64B b-rows.
#define O_H0R  0u           // 16 x 131072 = 2 MB
#define O_H1R  2097152u     // 16 x 131072 = 2 MB
#define O_BAR  4194304u     // 256 flags x 64 B

// ---- LDS byte offsets (131072 dynamic, single-f16 weight planes, 32 rows/WG) ----
#define E0W 0u             // 32 rows x 576  (x|h0), row 1152 B  = 36 KB
#define E1W 36864u         // 32 rows x 1024 (h0|h1), row 2048 B = 64 KB
#define D0W 0u             // 32 rows x 1024 (Weff|dWhh0) = 64 KB
#define D1W 65536u         // 32 rows x 1024 (dWih1|dWhh1) = 64 KB

__device__ __forceinline__ float sigf(float x) { return 1.0f / (1.0f + expf(-x)); }

__device__ __forceinline__ u16 f2h_bits(float f) {
    _Float16 h = (_Float16)f;
    return __builtin_bit_cast(u16, h);
}
__device__ __forceinline__ float h2f(u16 x) {
    return (float)__builtin_bit_cast(_Float16, x);
}

// Producer-side stores: agent-scope write-through (visible at MALL, no dirty L2 lines).
__device__ __forceinline__ void llc_store64(u64* p, u64 v) {
    __hip_atomic_store(p, v, __ATOMIC_RELAXED, __HIP_MEMORY_SCOPE_AGENT);
}
__device__ __forceinline__ void llc_store32(u32* p, u32 v) {
    __hip_atomic_store(p, v, __ATOMIC_RELAXED, __HIP_MEMORY_SCOPE_AGENT);
}

// ---- split-phase group barrier: atomic-free flags + wave-parallel poll ----
// arrive: drain own stores, then ONE sc1 store to this WG's private flag line.
__device__ __forceinline__ void gbar_arrive(int* flags, int w, int gen) {
    asm volatile("s_waitcnt vmcnt(0)" ::: "memory");
    __syncthreads();
    if (threadIdx.x == 0)
        __hip_atomic_store(flags + w * 16, gen, __ATOMIC_RELAXED, __HIP_MEMORY_SCOPE_AGENT);
}
// wait: wave 0's 64 lanes poll the group's 64 flags in parallel; lap-boundary
// fence (single L2 inv per WG, 1/16 cadence -- r14-proven) only when `inv`.
__device__ __forceinline__ void gbar_wait(int* flags, int gbase, int gen, bool inv) {
    if (threadIdx.x < 64) {
        while (__hip_atomic_load(flags + (gbase + threadIdx.x) * 16,
                                 __ATOMIC_RELAXED, __HIP_MEMORY_SCOPE_AGENT) < gen)
            __builtin_amdgcn_s_sleep(1);
    }
    __syncthreads();
    if (inv) {
        if (threadIdx.x == 0) __builtin_amdgcn_fence(__ATOMIC_ACQUIRE, "agent");
        __syncthreads();
    }
}

// store one weight element as single f16 into swizzled LDS plane (32 rows)
__device__ __forceinline__ void st_w(char* smem, unsigned base, unsigned K2,
                                     unsigned m, unsigned k, float v) {
    _Float16 hh = (_Float16)v;
    unsigned off = (m * K2 + k * 2) ^ ((m & 7) << 4);
    *(u16*)(smem + base + off) = __builtin_bit_cast(u16, hh);
}

// Issue ALL 16 chunk-loads of one f16 plane slice (uint4 = 8 f16 per lane per chunk).
__device__ __forceinline__ void load_plane(uint4 (&buf)[16], const u32* __restrict__ plane,
                                           unsigned loff) {
    #pragma unroll
    for (int i = 0; i < 16; ++i)
        buf[i] = *(const uint4*)(plane + (size_t)i * 2048 + loff);
}

// Consume one plane: B direct from registers, A row R from swizzled LDS f16.
__device__ __forceinline__ void cons_plane(const uint4 (&buf)[16], const char* __restrict__ smem,
                                           unsigned base, unsigned K2, unsigned wk0,
                                           unsigned R, unsigned qq, f32x4& acc) {
    const unsigned swz = (R & 7) << 4;
    #pragma unroll
    for (int i = 0; i < 16; ++i) {
        const unsigned wb = R * K2 + (wk0 + (unsigned)i * 32 + qq * 8) * 2;
        half8 av = *(const half8*)(smem + base + (wb ^ swz));
        half8 bv = __builtin_bit_cast(half8, buf[i]);
        acc = __builtin_amdgcn_mfma_f32_16x16x32_f16(av, bv, acc, 0, 0, 0);
    }
}

// encoder cell-A x-segment (K=64): B built on the fly from fp32 x rows (read-only)
__device__ __forceinline__ void seg_x(
    const char* smem, unsigned base, unsigned K2,
    const float* __restrict__ x, int t, unsigned bt, unsigned R, int lane, f32x4& acc) {
    const unsigned mm = lane & 15, qq = lane >> 4;
    const unsigned swz = (R & 7) << 4;
    const float* xp = x + ((size_t)(bt + mm) * T_ + t) * 64 + qq * 8;
    #pragma unroll
    for (int i = 0; i < 2; ++i) {
        float4 f0 = *(const float4*)(xp + i * 32);
        float4 f1 = *(const float4*)(xp + i * 32 + 4);
        float fs[8] = { f0.x, f0.y, f0.z, f0.w, f1.x, f1.y, f1.z, f1.w };
        half8 bv;
        #pragma unroll
        for (int j = 0; j < 8; ++j) bv[j] = (_Float16)fs[j];
        unsigned wb = (R * K2 + (qq * 8 + i * 32) * 2) ^ swz;
        half8 av = *(const half8*)(smem + base + wb);
        acc = __builtin_amdgcn_mfma_f32_16x16x32_f16(av, bv, acc, 0, 0, 0);
    }
}

// LSTM epilogue: lane owns 4 gate preacts of one (u,b); c in register.
// h -> f16; pair-pack with lane^16 (u and u+-1) -> one u32 sc1 store per pair.
__device__ __forceinline__ void epilogue_reg(f32x4 acc, const float* bz, int u, int b,
                                             float& cr, u32* hw, int lane) {
    float gi = sigf(acc[0] + bz[0]);
    float gf = sigf(acc[1] + bz[1]);
    float gt = tanhf(acc[2] + bz[2]);
    float go = sigf(acc[3] + bz[3]);
    float cn = gf * cr + gi * gt;
    cr = cn;
    float hv = go * tanhf(cn);
    u16 mybits = f2h_bits(hv);
    int other = __shfl_xor((int)(u32)mybits, 16);
    if (((lane >> 4) & 1) == 0) {   // even-u member of the pair stores
        u32 pk = (u32)mybits | (((u32)other & 0xFFFFu) << 16);
        unsigned idx = (unsigned)(u >> 5) * 2048 + (unsigned)b * 16 + ((unsigned)(u & 31) >> 1);
        llc_store32(hw + idx, pk);
    }
}

// out(t) = h1 @ linW.T + linb; group WG wl: batch bl = g*32 + (wl>>1), f-half = wl&1.
__device__ __forceinline__ void linear_out(const u32* __restrict__ h1p,
                                           const float* __restrict__ linW,
                                           const float* __restrict__ linb,
                                           float* __restrict__ out, int g, int wl,
                                           int tid, int t) {
    const int bl = g * 32 + (wl >> 1);
    const int kq = tid & 7;
    const int f  = (wl & 1) * 32 + (tid >> 3);
    float s = 0.f;
    #pragma unroll
    for (int c2 = 0; c2 < 2; ++c2) {
        const int ch = kq * 2 + c2;   // k chunk = k>>5
        const u64* ph = (const u64*)h1p + (size_t)ch * 1024 + (size_t)bl * 8;
        const float* wp = linW + (size_t)f * H_ + ch * 32;
        #pragma unroll
        for (int j = 0; j < 8; ++j) {     // each u64 = 4 f16
            u64 r = ph[j];
            s += h2f((u16)r)         * wp[4 * j + 0];
            s += h2f((u16)(r >> 16)) * wp[4 * j + 1];
            s += h2f((u16)(r >> 32)) * wp[4 * j + 2];
            s += h2f((u16)(r >> 48)) * wp[4 * j + 3];
        }
    }
    s += __shfl_xor(s, 1);
    s += __shfl_xor(s, 2);
    s += __shfl_xor(s, 4);
    if (kq == 0)
        out[((size_t)bl * T_ + (255 - t)) * 64 + f] = s + linb[f];
}

__global__ __launch_bounds__(NTHR, 1) void lstm_persist(
    const float* __restrict__ x,
    const float* __restrict__ eWih0, const float* __restrict__ eWhh0,
    const float* __restrict__ ebih0, const float* __restrict__ ebhh0,
    const float* __restrict__ eWih1, const float* __restrict__ eWhh1,
    const float* __restrict__ ebih1, const float* __restrict__ ebhh1,
    const float* __restrict__ dWih0, const float* __restrict__ dWhh0,
    const float* __restrict__ dbih0, const float* __restrict__ dbhh0,
    const float* __restrict__ dWih1, const float* __restrict__ dWhh1,
    const float* __restrict__ dbih1, const float* __restrict__ dbhh1,
    const float* __restrict__ linW,  const float* __restrict__ linb,
    float* __restrict__ out, char* __restrict__ wsb, int* __restrict__ flags) {
    extern __shared__ char smem[];
    const int w = blockIdx.x, tid = threadIdx.x;
    const int lane = tid & 63, wave = tid >> 6;   // wave 0..3

    // group structure: 4 groups x 64 WGs; group owns 32 batches, WG owns 8 u's.
    const int g = w >> 6;
    const int wl = w & 63;
    const int gbase = g * WPG;
    const int u_base = wl * 8;
    const int mh = wave >> 1;                 // m-half: rows [mh*16, mh*16+16)
    const int bh = wave & 1;                  // b-half within group's 32 batches
    const int u = u_base + mh * 4 + (lane >> 4);
    const unsigned bt = (unsigned)(g * 32 + bh * 16);
    const int b = (int)bt + (lane & 15);
    const unsigned R = (unsigned)(mh * 16 + (lane & 15));   // LDS A row (0..31)
    const unsigned qq = (unsigned)(lane >> 4);
    const unsigned loff = (bt + (unsigned)(lane & 15)) * 16 + qq * 4;

    // ring-slot accessors: slot = step & 15; negative steps wrap.
    #define H0S(t) ((u32*)(wsb + O_H0R + (unsigned)((t) & 15) * 131072u))
    #define H1S(t) ((u32*)(wsb + O_H1R + (unsigned)((t) & 15) * 131072u))
    int gen = 0;

    // ================= INIT (group-local) =================
    {   // zero this group's b-slice of h0 slot15, h1 slots 14,15
        const int gtid = wl * NTHR + tid;     // 0..16383 within group
        if (gtid < 12288) {
            const int slot  = gtid >> 12;             // 0..2
            const int rem   = gtid & 4095;
            const int chunk = rem >> 8;
            const int brow  = (rem & 255) >> 3;
            const int q     = rem & 7;
            u64* base = (slot == 0) ? (u64*)(wsb + O_H0R + 15u * 131072u)
                      : (slot == 1) ? (u64*)(wsb + O_H1R + 14u * 131072u)
                                    : (u64*)(wsb + O_H1R + 15u * 131072u);
            llc_store64(base + (size_t)chunk * 1024 + (size_t)(g * 32 + brow) * 8 + q, 0ULL);
        }
    }
    // per-lane bias registers (incl. beff fold); c in registers
    float bzA[4], bzB[4], bzD0[4], bzD0b[4], bzD1[4];
    #pragma unroll
    for (int gg = 0; gg < 4; ++gg) {
        const int gr = gg * H_ + u;
        bzA[gg] = ebih0[gr] + ebhh0[gr];
        bzB[gg] = ebih1[gr] + ebhh1[gr];
        float d0 = dbih0[gr] + dbhh0[gr];
        bzD0[gg] = d0;
        float s = 0.f;
        for (int f = 0; f < 64; ++f) s += dWih0[(size_t)gr * 64 + f] * linb[f];
        bzD0b[gg] = d0 + s;
        bzD1[gg] = dbih1[gr] + dbhh1[gr];
    }
    float c0r = 0.f, c1r = 0.f;

    // encoder weights -> swizzled LDS f16 (32 rows: 8 u's x 4 gates)
    for (int mr = 0; mr < 32; ++mr) {
        const int gr = (mr & 3) * H_ + u_base + (mr >> 2);
        for (int k = tid; k < 576; k += NTHR) {
            float v = (k < 64) ? eWih0[(size_t)gr * 64 + k] : eWhh0[(size_t)gr * H_ + (k - 64)];
            st_w(smem, E0W, 1152, mr, k, v);
        }
        for (int k = tid; k < 1024; k += NTHR) {
            float v = (k < 512) ? eWih1[(size_t)gr * H_ + k] : eWhh1[(size_t)gr * H_ + (k - 512)];
            st_w(smem, E1W, 2048, mr, k, v);
        }
    }
    gbar_arrive(flags, w, ++gen);
    gbar_wait(flags, gbase, gen, false);

    uint4 P[16], Q[16];

    // ================= ENCODER: depth-2 pipeline, 257 phases (r14-proven) =================
    // phase p: cellA(t=p) || cellB(t=p-1). Both consume h0(p-1) (plane P shared).
    for (int p = 0; p <= T_; ++p) {
        gbar_arrive(flags, w, ++gen);
        f32x4 a = {0,0,0,0}, e = {0,0,0,0};
        if (p < T_) seg_x(smem, E0W, 1152, x, p, bt, R, lane, a);   // pre-wait: x read-only
        gbar_wait(flags, gbase, gen, p > 0 && (p & 15) == 0);
        load_plane(P, H0S(p - 1), loff);    // h0(p-1), written last phase
        if (p >= 1) load_plane(Q, H1S(p - 2), loff);   // h1(p-2), written last phase
        if (p < T_) cons_plane(P, smem, E0W, 1152, 64, R, qq, a);
        if (p >= 1) {
            cons_plane(P, smem, E1W, 2048, 0,   R, qq, e);
            cons_plane(Q, smem, E1W, 2048, 512, R, qq, e);
        }
        if (p < T_)  epilogue_reg(a, bzA, u, b, c0r, H0S(p), lane);
        if (p >= 1)  epilogue_reg(e, bzB, u, b, c1r, H1S(p - 1), lane);
    }

    // ================= TRANSITION: decoder weights -> LDS (WG-local) =================
    __syncthreads();
    for (int mr = 0; mr < 32; ++mr) {
        const int gr = (mr & 3) * H_ + u_base + (mr >> 2);
        const float* wr = dWih0 + (size_t)gr * 64;
        for (int c = tid; c < 512; c += NTHR) {
            float s = 0.f;
            #pragma unroll 8
            for (int f = 0; f < 64; ++f) s += wr[f] * linW[(size_t)f * H_ + c];  // Weff
            st_w(smem, D0W, 2048, mr, c, s);
            st_w(smem, D0W, 2048, mr, 512 + c, dWhh0[(size_t)gr * H_ + c]);
            st_w(smem, D1W, 2048, mr, c,       dWih1[(size_t)gr * H_ + c]);
            st_w(smem, D1W, 2048, mr, 512 + c, dWhh1[(size_t)gr * H_ + c]);
        }
    }
    __syncthreads();

    // ================= DECODER: 512 phases, 1 fresh plane-load per phase =================
    // Register carry: P holds h1(t-1) (loaded in dec0), Q holds h0 (loaded in dec1).
    // Stale-register half consumed PRE-wait; linear_out(t-1) in dec1's pre-wait slot
    // (input certified by dec0(t)'s wait -- one full barrier after producers drained).
    for (int t = 0; t < T_; ++t) {
        {   // ---- dec0(t): Weff.h1(t-1) (or x-proj at t=0) + dWhh0.h0(t-1) ----
            gbar_arrive(flags, w, ++gen);
            f32x4 a = {0,0,0,0};
            if (t > 0) {
                cons_plane(Q, smem, D0W, 2048, 512, R, qq, a);   // pre-wait: h0(t-1) in regs
            } else {
                const float* xr = x + ((size_t)b * T_ + (T_ - 1)) * 64;
                #pragma unroll
                for (int gg = 0; gg < 4; ++gg) {
                    const float* wr = dWih0 + (size_t)(gg * H_ + u) * 64;
                    float s = 0.f;
                    for (int f = 0; f < 64; ++f) s += wr[f] * xr[f];
                    a[gg] = s;
                }
            }
            gbar_wait(flags, gbase, gen, t > 0 && (t & 15) == 0);
            if (t > 0) {
                load_plane(P, H1S(t - 1), loff);                 // fresh h1(t-1)
                cons_plane(P, smem, D0W, 2048, 0, R, qq, a);
            } else {
                load_plane(Q, H0S(-1), loff);                    // h0(-1) = enc h0(255)
                cons_plane(Q, smem, D0W, 2048, 512, R, qq, a);
            }
            epilogue_reg(a, (t > 0) ? bzD0b : bzD0, u, b, c0r, H0S(t), lane);
        }
        {   // ---- dec1(t): dWih1.h0(t) + dWhh1.h1(t-1) ----
            gbar_arrive(flags, w, ++gen);
            f32x4 e = {0,0,0,0};
            if (t > 0) {
                cons_plane(P, smem, D1W, 2048, 512, R, qq, e);   // pre-wait: h1(t-1) in regs
                linear_out(H1S(t - 1), linW, linb, out, g, wl, tid, t - 1);  // off crit path
            }
            gbar_wait(flags, gbase, gen, false);
            load_plane(Q, H0S(t), loff);                         // fresh h0(t)
            if (t == 0) {
                load_plane(P, H1S(-1), loff);                    // h1(-1) = enc h1(255)
                cons_plane(P, smem, D1W, 2048, 512, R, qq, e);
            }
            cons_plane(Q, smem, D1W, 2048, 0, R, qq, e);
            epilogue_reg(e, bzD1, u, b, c1r, H1S(t), lane);
        }
    }
    // final output (t=255): needs ALL group WGs' h1(255) -> proper group barrier
    gbar_arrive(flags, w, ++gen);
    gbar_wait(flags, gbase, gen, false);
    linear_out(H1S(255), linW, linb, out, g, wl, tid, 255);
}

extern "C" void kernel_launch(void* const* d_in, const int* in_sizes, int n_in,
                              void* d_out, int out_size, void* d_ws, size_t ws_size,
                              hipStream_t stream) {
    (void)in_sizes; (void)n_in; (void)out_size; (void)ws_size;
    const float* x     = (const float*)d_in[0];
    const float* eWih0 = (const float*)d_in[1];
    const float* eWhh0 = (const float*)d_in[2];
    const float* ebih0 = (const float*)d_in[3];
    const float* ebhh0 = (const float*)d_in[4];
    const float* eWih1 = (const float*)d_in[5];
    const float* eWhh1 = (const float*)d_in[6];
    const float* ebih1 = (const float*)d_in[7];
    const float* ebhh1 = (const float*)d_in[8];
    const float* dWih0 = (const float*)d_in[9];
    const float* dWhh0 = (const float*)d_in[10];
    const float* dbih0 = (const float*)d_in[11];
    const float* dbhh0 = (const float*)d_in[12];
    const float* dWih1 = (const float*)d_in[13];
    const float* dWhh1 = (const float*)d_in[14];
    const float* dbih1 = (const float*)d_in[15];
    const float* dbhh1 = (const float*)d_in[16];
    const float* linW  = (const float*)d_in[17];
    const float* linb  = (const float*)d_in[18];

    char* wsb  = (char*)d_ws;
    int* flags = (int*)(wsb + O_BAR);

    static const int lds_bytes = 131072;
    hipFuncSetAttribute((const void*)lstm_persist,
                        hipFuncAttributeMaxDynamicSharedMemorySize, lds_bytes);

    hipMemsetAsync(flags, 0, NWG * 64, stream);

    hipLaunchKernelGGL(lstm_persist, dim3(NWG), dim3(NTHR), lds_bytes, stream,
                       x, eWih0, eWhh0, ebih0, ebhh0, eWih1, eWhh1, ebih1, ebhh1,
                       dWih0, dWhh0, dbih0, dbhh0, dWih1, dWhh1, dbih1, dbhh1,
                       linW, linb, (float*)d_out, wsb, flags);
}